// Round 4
// baseline (354.011 us; speedup 1.0000x reference)
//
#include <hip/hip_runtime.h>
#include <math.h>

#define NB 8
#define HH 56
#define WWD 56
#define CC 256
#define PIX (NB*HH*WWD)   // 25088

typedef __attribute__((ext_vector_type(8))) short bf16x8;
typedef __attribute__((ext_vector_type(4))) float f32x4;

__device__ __forceinline__ float gelu_exact(float v) {
    return 0.5f * v * (1.0f + erff(v * 0.70710678118654752f));
}
__device__ __forceinline__ unsigned short f2bf(float f) {
    unsigned u = __float_as_uint(f);
    unsigned r = (u + 0x7fffu + ((u >> 16) & 1u)) >> 16;
    return (unsigned short)r;
}
__device__ __forceinline__ float bf2f(unsigned short b) {
    return __uint_as_float(((unsigned)b) << 16);
}
__device__ __forceinline__ void gl_lds16(const void* g, void* l) {
    __builtin_amdgcn_global_load_lds(
        (const __attribute__((address_space(1))) void*)g,
        (__attribute__((address_space(3))) void*)l, 16, 0, 0);
}
__device__ __forceinline__ void wave_reduce2(float& s, float& sq) {
    #pragma unroll
    for (int o = 32; o >= 1; o >>= 1) {
        s  += __shfl_xor(s, o);
        sq += __shfl_xor(sq, o);
    }
}

// fp32 -> bf16 transposed weight: Bt[n*K + k] = W[k*N + n] (zero pad rows n>=N)
__global__ __launch_bounds__(256) void wtrans_kernel(
    const float* __restrict__ W, unsigned short* __restrict__ Bt,
    int K, int N, int Npad)
{
    int i = blockIdx.x * 256 + threadIdx.x;
    if (i >= Npad * K) return;
    int n = i / K, k = i - n * K;
    float v = (n < N) ? W[(size_t)k * N + n] : 0.f;
    Bt[i] = f2bf(v);
}

// concat offset(288) + mask(144) weights into one 512xK bf16 Bt + concat bias
__global__ __launch_bounds__(256) void wtrans_om_kernel(
    const float* __restrict__ offw, const float* __restrict__ offb,
    const float* __restrict__ mskw, const float* __restrict__ mskb,
    unsigned short* __restrict__ Bt, float* __restrict__ bias)
{
    int i = blockIdx.x * 256 + threadIdx.x;   // over 512*256
    int n = i >> 8, k = i & 255;
    float v = (n < 288) ? offw[(size_t)k*288 + n]
            : (n < 432) ? mskw[(size_t)k*144 + (n-288)] : 0.f;
    Bt[i] = f2bf(v);
    if (i < 512)
        bias[i] = (i < 288) ? offb[i] : (i < 432) ? mskb[i-288] : 0.f;
}

// LayerNorm over C=256, fp32 in -> bf16 out. One wave/pixel.
__global__ __launch_bounds__(256) void ln_bf_kernel(
    const float* __restrict__ in, const float* __restrict__ g,
    const float* __restrict__ b, unsigned short* __restrict__ out)
{
    int wave = threadIdx.x >> 6, lane = threadIdx.x & 63;
    int pix = blockIdx.x * 4 + wave;
    int c0 = lane * 4;
    float4 v = *reinterpret_cast<const float4*>(&in[(size_t)pix * CC + c0]);
    float s = v.x + v.y + v.z + v.w;
    float sq = v.x*v.x + v.y*v.y + v.z*v.z + v.w*v.w;
    wave_reduce2(s, sq);
    float mu = s * (1.0f/256.0f);
    float var = sq * (1.0f/256.0f) - mu*mu;
    float rs = rsqrtf(var + 1e-6f);
    float4 gv = *reinterpret_cast<const float4*>(&g[c0]);
    float4 bv = *reinterpret_cast<const float4*>(&b[c0]);
    ushort4 o;
    o.x = f2bf((v.x-mu)*rs*gv.x + bv.x);
    o.y = f2bf((v.y-mu)*rs*gv.y + bv.y);
    o.z = f2bf((v.z-mu)*rs*gv.z + bv.z);
    o.w = f2bf((v.w-mu)*rs*gv.w + bv.w);
    *reinterpret_cast<ushort4*>(&out[(size_t)pix * CC + c0]) = o;
}

// 3x3 depthwise conv (bf16 in) + bias + LN + exact GELU -> bf16 out.
__global__ __launch_bounds__(256) void dwconv_ln_gelu_kernel(
    const unsigned short* __restrict__ xl, const float* __restrict__ w9,
    const float* __restrict__ cb, const float* __restrict__ lg,
    const float* __restrict__ lb, unsigned short* __restrict__ out)
{
    int bid = blockIdx.x;
    int wg = (bid & 7) * (gridDim.x >> 3) + (bid >> 3);
    int wave = threadIdx.x >> 6, lane = threadIdx.x & 63;
    int pix = wg * 4 + wave;
    int n = pix / (HH*WWD); int rem = pix % (HH*WWD);
    int h = rem / WWD, w = rem % WWD;
    int c0 = lane * 4;
    float a0 = cb[c0+0], a1 = cb[c0+1], a2 = cb[c0+2], a3 = cb[c0+3];
    #pragma unroll
    for (int t = 0; t < 9; ++t) {
        int hh = h + t/3 - 1, wx = w + t%3 - 1;
        if (hh >= 0 && hh < HH && wx >= 0 && wx < WWD) {
            ushort4 xv = *reinterpret_cast<const ushort4*>(
                &xl[(((size_t)n*HH + hh)*WWD + wx)*CC + c0]);
            a0 += bf2f(xv.x) * w9[(c0+0)*9 + t];
            a1 += bf2f(xv.y) * w9[(c0+1)*9 + t];
            a2 += bf2f(xv.z) * w9[(c0+2)*9 + t];
            a3 += bf2f(xv.w) * w9[(c0+3)*9 + t];
        }
    }
    float s = a0+a1+a2+a3;
    float sq = a0*a0+a1*a1+a2*a2+a3*a3;
    wave_reduce2(s, sq);
    float mu = s*(1.f/256.f), var = sq*(1.f/256.f) - mu*mu;
    float rs = rsqrtf(var + 1e-6f);
    ushort4 o;
    o.x = f2bf(gelu_exact((a0-mu)*rs*lg[c0+0] + lb[c0+0]));
    o.y = f2bf(gelu_exact((a1-mu)*rs*lg[c0+1] + lb[c0+1]));
    o.z = f2bf(gelu_exact((a2-mu)*rs*lg[c0+2] + lb[c0+2]));
    o.w = f2bf(gelu_exact((a3-mu)*rs*lg[c0+3] + lb[c0+3]));
    *reinterpret_cast<ushort4*>(&out[(size_t)pix * CC + c0]) = o;
}

// ---------------- bf16 MFMA GEMM (2-phase double-buffered, BK=64) ----------------
// C(MxN) = A(MxK,bf16) @ Bt(NpadxK,bf16)^T + bias.
// 128x128 tile, 4 waves (2x2 of 64x64), mfma_f32_16x16x32_bf16.
// EPI 1: bf16 gelu. EPI 2: fp32 extra1+extra2[c]*v. EPI 3: bf16 plain.
// EPI 4: fused off+mask -> Cf (cols<288) / Cf2 (288<=c<432).
template<int EPI>
__global__ __launch_bounds__(256) void gemm_bf16(
    const unsigned short* __restrict__ A, const unsigned short* __restrict__ Bt,
    const float* __restrict__ bias, float* __restrict__ Cf, float* __restrict__ Cf2,
    unsigned short* __restrict__ Cb, int M, int N, int K,
    const float* __restrict__ extra1, const float* __restrict__ extra2)
{
    __shared__ unsigned short Al[2][8192];   // [buf][kb:8][row:128][j:8]
    __shared__ unsigned short Bl[2][8192];
    const int tid = threadIdx.x;
    const int wave = tid >> 6, lane = tid & 63;
    const int wr = wave >> 1, wc = wave & 1;
    const int lm = lane & 15, kq = lane >> 4;

    // XCD-chunked bijective remap of linear block id (nwg % 8 == 0)
    int bid = blockIdx.x + blockIdx.y * gridDim.x;
    int nwg = gridDim.x * gridDim.y;
    int wg = (bid & 7) * (nwg >> 3) + (bid >> 3);
    const int m0 = (wg / gridDim.x) * 128;
    const int n0 = (wg % gridDim.x) * 128;

    f32x4 acc[4][4];
    #pragma unroll
    for (int i = 0; i < 4; ++i)
        #pragma unroll
        for (int j = 0; j < 4; ++j)
            acc[i][j] = (f32x4){0.f, 0.f, 0.f, 0.f};

    const int arow = wr*64 + lm;
    const int brow = wc*64 + lm;

    // stage one BK=64 tile of A and Bt into buffer `buf`
    auto STAGE = [&](int buf, int k0) {
        #pragma unroll
        for (int i = 0; i < 4; ++i) {
            int idx = i*256 + tid;
            int kb = idx >> 7, row = idx & 127;
            int ldsoff = buf*16384 + i*4096 + wave*1024;   // bytes, wave-uniform
            gl_lds16(A  + (size_t)(m0+row)*K + k0 + kb*8, (char*)Al + ldsoff);
            gl_lds16(Bt + (size_t)(n0+row)*K + k0 + kb*8, (char*)Bl + ldsoff);
        }
    };

    const int nsteps = K >> 6;
    STAGE(0, 0);
    __syncthreads();
    for (int t = 0; t < nsteps; ++t) {
        int cur = t & 1;
        if (t + 1 < nsteps) STAGE(cur ^ 1, (t+1) << 6);
        #pragma unroll
        for (int ks = 0; ks < 2; ++ks) {
            bf16x8 af[4], bv[4];
            #pragma unroll
            for (int mi = 0; mi < 4; ++mi)
                af[mi] = *reinterpret_cast<const bf16x8*>(
                    &Al[cur][((ks*4+kq)*128 + arow + mi*16)*8]);
            #pragma unroll
            for (int ni = 0; ni < 4; ++ni)
                bv[ni] = *reinterpret_cast<const bf16x8*>(
                    &Bl[cur][((ks*4+kq)*128 + brow + ni*16)*8]);
            #pragma unroll
            for (int mi = 0; mi < 4; ++mi)
                #pragma unroll
                for (int ni = 0; ni < 4; ++ni)
                    acc[mi][ni] = __builtin_amdgcn_mfma_f32_16x16x32_bf16(
                        af[mi], bv[ni], acc[mi][ni], 0, 0, 0);
        }
        __syncthreads();
    }

    #pragma unroll
    for (int mi = 0; mi < 4; ++mi) {
        #pragma unroll
        for (int ni = 0; ni < 4; ++ni) {
            int c = n0 + wc*64 + ni*16 + lm;
            if (c < N) {
                float bb = bias[c];
                #pragma unroll
                for (int j = 0; j < 4; ++j) {
                    int r = m0 + wr*64 + mi*16 + kq*4 + j;
                    float v = acc[mi][ni][j] + bb;
                    if (EPI == 1) {
                        Cb[(size_t)r*N + c] = f2bf(gelu_exact(v));
                    } else if (EPI == 2) {
                        size_t gi = (size_t)r*N + c;
                        Cf[gi] = extra1[gi] + extra2[c]*v;
                    } else if (EPI == 3) {
                        Cb[(size_t)r*N + c] = f2bf(v);
                    } else {
                        if (c < 288)      Cf [(size_t)r*288 + c]       = v;
                        else if (c < 432) Cf2[(size_t)r*144 + (c-288)] = v;
                    }
                }
            }
        }
    }
}

// softmax over P=9 per (pixel, group), in place (fp32)
__global__ __launch_bounds__(256) void softmax9_kernel(float* __restrict__ m, int total)
{
    int i = blockIdx.x*256 + threadIdx.x;
    if (i >= total) return;
    float* p = m + (size_t)i*9;
    float v[9]; float mx = -1e30f;
    #pragma unroll
    for (int j = 0; j < 9; ++j) { v[j] = p[j]; mx = fmaxf(mx, v[j]); }
    float s = 0.f;
    #pragma unroll
    for (int j = 0; j < 9; ++j) { v[j] = expf(v[j]-mx); s += v[j]; }
    float inv = 1.f/s;
    #pragma unroll
    for (int j = 0; j < 9; ++j) p[j] = v[j]*inv;
}

__device__ __forceinline__ void tap4b(const unsigned short* __restrict__ img, int yi, int xi,
                                      float wgt, float4& s) {
    // padded coords; nonzero region is [1,56]
    if (yi >= 1 && yi <= 56 && xi >= 1 && xi <= 56) {
        ushort4 v = *reinterpret_cast<const ushort4*>(
            &img[(((size_t)(yi-1))*WWD + (xi-1)) * CC]);
        s.x += wgt*bf2f(v.x); s.y += wgt*bf2f(v.y);
        s.z += wgt*bf2f(v.z); s.w += wgt*bf2f(v.w);
    }
}

// Deformable sampling + mask aggregation. 1 wave/pixel; lane = (g, c4).
__global__ __launch_bounds__(256) void dcn_sample_kernel(
    const unsigned short* __restrict__ xproj, const float* __restrict__ offs,
    const float* __restrict__ msk, unsigned short* __restrict__ dcn)
{
    int bid = blockIdx.x;
    int wg = (bid & 7) * (gridDim.x >> 3) + (bid >> 3);
    int wave = threadIdx.x >> 6, lane = threadIdx.x & 63;
    int pix = wg * 4 + wave;
    int n = pix / (HH*WWD); int rem = pix % (HH*WWD);
    int h = rem / WWD, w = rem % WWD;
    int g = lane >> 2, c4 = lane & 3;
    const float* op = offs + (size_t)pix*288 + g*18;
    const float* mp = msk + (size_t)pix*144 + g*9;
    const unsigned short* img = xproj + (size_t)n*(HH*WWD*CC) + g*16 + c4*4;
    float4 acc = {0.f, 0.f, 0.f, 0.f};
    #pragma unroll
    for (int p = 0; p < 9; ++p) {
        float ox = op[p*2+0], oy = op[p*2+1];
        float xs = (float)(w + p/3) + ox;   // padded-image coords
        float ys = (float)(h + p%3) + oy;
        float x0f = floorf(xs), y0f = floorf(ys);
        float lx = xs - x0f, ly = ys - y0f;
        int x0 = (int)x0f, y0 = (int)y0f;
        float4 s = {0.f, 0.f, 0.f, 0.f};
        tap4b(img, y0,   x0,   (1.f-lx)*(1.f-ly), s);
        tap4b(img, y0,   x0+1, lx*(1.f-ly),       s);
        tap4b(img, y0+1, x0,   (1.f-lx)*ly,       s);
        tap4b(img, y0+1, x0+1, lx*ly,             s);
        float m = mp[p];
        acc.x += m*s.x; acc.y += m*s.y; acc.z += m*s.z; acc.w += m*s.w;
    }
    ushort4 o;
    o.x = f2bf(acc.x); o.y = f2bf(acc.y); o.z = f2bf(acc.z); o.w = f2bf(acc.w);
    *reinterpret_cast<ushort4*>(&dcn[(size_t)pix*CC + g*16 + c4*4]) = o;
}

extern "C" void kernel_launch(void* const* d_in, const int* in_sizes, int n_in,
                              void* d_out, int out_size, void* d_ws, size_t ws_size,
                              hipStream_t stream)
{
    const float* x    = (const float*)d_in[0];
    const float* n1g  = (const float*)d_in[1];
    const float* n1b  = (const float*)d_in[2];
    const float* n2g  = (const float*)d_in[3];
    const float* n2b  = (const float*)d_in[4];
    const float* g1   = (const float*)d_in[5];
    const float* g2   = (const float*)d_in[6];
    const float* dww  = (const float*)d_in[7];
    const float* dwb  = (const float*)d_in[8];
    const float* dlng = (const float*)d_in[9];
    const float* dlnb = (const float*)d_in[10];
    const float* offw = (const float*)d_in[11];
    const float* offb = (const float*)d_in[12];
    const float* mskw = (const float*)d_in[13];
    const float* mskb = (const float*)d_in[14];
    const float* inw  = (const float*)d_in[15];
    const float* inb  = (const float*)d_in[16];
    const float* outw = (const float*)d_in[17];
    const float* outb = (const float*)d_in[18];
    const float* f1w  = (const float*)d_in[19];
    const float* f1b  = (const float*)d_in[20];
    const float* f2w  = (const float*)d_in[21];
    const float* f2b  = (const float*)d_in[22];
    float* out = (float*)d_out;

    char* base = (char*)d_ws;
    // arena (bytes)
    unsigned short* xl_bf    = (unsigned short*)(base + 0);          // 12,845,056 B
    unsigned short* xproj_bf = (unsigned short*)(base + 12845056);   // 12,845,056 B
    float*          xres     = (float*)(base + 25690112);            // 25,690,112 B
    unsigned short* x1_bf    = (unsigned short*)(base + 51380224);   // 12,845,056 B
    float*          offs     = (float*)(base + 64225280);            // 28,901,376 B
    float*          msk      = (float*)(base + 93126656);            // 14,450,688 B
    unsigned short* dcn_bf   = xl_bf;                                 // reuse region A
    unsigned short* y2_bf    = x1_bf;                                 // reuse region C
    unsigned short* h1       = (unsigned short*)(base + 64225280);   // 51,380,224 B (over offs+msk)
    unsigned short* btb      = (unsigned short*)(base + 115605504);
    unsigned short* bt_in  = btb + 0;          // 256x256
    unsigned short* bt_om  = btb + 65536;      // 512x256
    unsigned short* bt_out = btb + 196608;     // 256x256
    unsigned short* bt_fc1 = btb + 262144;     // 1024x256
    unsigned short* bt_fc2 = btb + 524288;     // 256x1024
    float*          bias_om = (float*)(btb + 786432);  // 512 floats

    // 0. weight transposes (fp32 -> bf16, N-major)
    wtrans_kernel<<<256,  256, 0, stream>>>(inw,  bt_in,  256, 256,  256);
    wtrans_om_kernel<<<512, 256, 0, stream>>>(offw, offb, mskw, mskb, bt_om, bias_om);
    wtrans_kernel<<<256,  256, 0, stream>>>(outw, bt_out, 256, 256,  256);
    wtrans_kernel<<<1024, 256, 0, stream>>>(f1w,  bt_fc1, 256, 1024, 1024);
    wtrans_kernel<<<1024, 256, 0, stream>>>(f2w,  bt_fc2, 1024, 256, 256);

    // 1. LN1 -> xl (bf16)
    ln_bf_kernel<<<PIX/4, 256, 0, stream>>>(x, n1g, n1b, xl_bf);
    // 2. in_proj -> xproj (bf16)
    gemm_bf16<3><<<dim3(2,196), 256, 0, stream>>>(xl_bf, bt_in, inb, nullptr, nullptr,
        xproj_bf, PIX, 256, 256, nullptr, nullptr);
    // 3. depthwise conv + LN + GELU -> x1 (bf16)
    dwconv_ln_gelu_kernel<<<PIX/4, 256, 0, stream>>>(xl_bf, dww, dwb, dlng, dlnb, x1_bf);
    // 4. fused offset+mask GEMM (fp32 out, routed)
    gemm_bf16<4><<<dim3(4,196), 256, 0, stream>>>(x1_bf, bt_om, bias_om, offs, msk,
        nullptr, PIX, 512, 256, nullptr, nullptr);
    // 5. softmax over P
    softmax9_kernel<<<(PIX*16)/256, 256, 0, stream>>>(msk, PIX*16);
    // 6. deformable sampling -> dcn (bf16, reuses xl region)
    dcn_sample_kernel<<<PIX/4, 256, 0, stream>>>(xproj_bf, offs, msk, dcn_bf);
    // 7. out_proj + residual: xres = x + gamma1*(dcn@out_w + out_b)  (fp32)
    gemm_bf16<2><<<dim3(2,196), 256, 0, stream>>>(dcn_bf, bt_out, outb, xres, nullptr,
        nullptr, PIX, 256, 256, x, g1);
    // 8. LN2 -> y2 (bf16, reuses x1 region)
    ln_bf_kernel<<<PIX/4, 256, 0, stream>>>(xres, n2g, n2b, y2_bf);
    // 9. fc1 + gelu -> h1 (bf16)
    gemm_bf16<1><<<dim3(8,196), 256, 0, stream>>>(y2_bf, bt_fc1, f1b, nullptr, nullptr,
        h1, PIX, 1024, 256, nullptr, nullptr);
    // 10. fc2 + residual -> out (fp32)
    gemm_bf16<2><<<dim3(2,196), 256, 0, stream>>>(h1, bt_fc2, f2b, out, nullptr,
        nullptr, PIX, 256, 1024, xres, g2);
}

// Round 5
// 341.980 us; speedup vs baseline: 1.0352x; 1.0352x over previous
//
#include <hip/hip_runtime.h>
#include <math.h>

#define NB 8
#define HH 56
#define WWD 56
#define CC 256
#define PIX (NB*HH*WWD)   // 25088

typedef __attribute__((ext_vector_type(8))) short bf16x8;
typedef __attribute__((ext_vector_type(4))) float f32x4;

__device__ __forceinline__ float gelu_exact(float v) {
    return 0.5f * v * (1.0f + erff(v * 0.70710678118654752f));
}
__device__ __forceinline__ unsigned short f2bf(float f) {
    unsigned u = __float_as_uint(f);
    unsigned r = (u + 0x7fffu + ((u >> 16) & 1u)) >> 16;
    return (unsigned short)r;
}
__device__ __forceinline__ float bf2f(unsigned short b) {
    return __uint_as_float(((unsigned)b) << 16);
}
__device__ __forceinline__ void gl_lds16(const void* g, void* l) {
    __builtin_amdgcn_global_load_lds(
        (const __attribute__((address_space(1))) void*)g,
        (__attribute__((address_space(3))) void*)l, 16, 0, 0);
}
__device__ __forceinline__ void wave_reduce2(float& s, float& sq) {
    #pragma unroll
    for (int o = 32; o >= 1; o >>= 1) {
        s  += __shfl_xor(s, o);
        sq += __shfl_xor(sq, o);
    }
}

// fp32 -> bf16 transposed weight: Bt[n*K + k] = W[k*N + n] (zero pad rows n>=N)
__global__ __launch_bounds__(256) void wtrans_kernel(
    const float* __restrict__ W, unsigned short* __restrict__ Bt,
    int K, int N, int Npad)
{
    int i = blockIdx.x * 256 + threadIdx.x;
    if (i >= Npad * K) return;
    int n = i / K, k = i - n * K;
    float v = (n < N) ? W[(size_t)k * N + n] : 0.f;
    Bt[i] = f2bf(v);
}

// concat offset(288) + mask(144) weights into one 512xK bf16 Bt + concat bias
__global__ __launch_bounds__(256) void wtrans_om_kernel(
    const float* __restrict__ offw, const float* __restrict__ offb,
    const float* __restrict__ mskw, const float* __restrict__ mskb,
    unsigned short* __restrict__ Bt, float* __restrict__ bias)
{
    int i = blockIdx.x * 256 + threadIdx.x;   // over 512*256
    int n = i >> 8, k = i & 255;
    float v = (n < 288) ? offw[(size_t)k*288 + n]
            : (n < 432) ? mskw[(size_t)k*144 + (n-288)] : 0.f;
    Bt[i] = f2bf(v);
    if (i < 512)
        bias[i] = (i < 288) ? offb[i] : (i < 432) ? mskb[i-288] : 0.f;
}

// LayerNorm over C=256, fp32 in -> bf16 out. One wave/pixel.
__global__ __launch_bounds__(256) void ln_bf_kernel(
    const float* __restrict__ in, const float* __restrict__ g,
    const float* __restrict__ b, unsigned short* __restrict__ out)
{
    int wave = threadIdx.x >> 6, lane = threadIdx.x & 63;
    int pix = blockIdx.x * 4 + wave;
    int c0 = lane * 4;
    float4 v = *reinterpret_cast<const float4*>(&in[(size_t)pix * CC + c0]);
    float s = v.x + v.y + v.z + v.w;
    float sq = v.x*v.x + v.y*v.y + v.z*v.z + v.w*v.w;
    wave_reduce2(s, sq);
    float mu = s * (1.0f/256.0f);
    float var = sq * (1.0f/256.0f) - mu*mu;
    float rs = rsqrtf(var + 1e-6f);
    float4 gv = *reinterpret_cast<const float4*>(&g[c0]);
    float4 bv = *reinterpret_cast<const float4*>(&b[c0]);
    ushort4 o;
    o.x = f2bf((v.x-mu)*rs*gv.x + bv.x);
    o.y = f2bf((v.y-mu)*rs*gv.y + bv.y);
    o.z = f2bf((v.z-mu)*rs*gv.z + bv.z);
    o.w = f2bf((v.w-mu)*rs*gv.w + bv.w);
    *reinterpret_cast<ushort4*>(&out[(size_t)pix * CC + c0]) = o;
}

// 3x3 depthwise conv (bf16 in) + bias + LN + exact GELU -> bf16 out.
__global__ __launch_bounds__(256) void dwconv_ln_gelu_kernel(
    const unsigned short* __restrict__ xl, const float* __restrict__ w9,
    const float* __restrict__ cb, const float* __restrict__ lg,
    const float* __restrict__ lb, unsigned short* __restrict__ out)
{
    int bid = blockIdx.x;
    int wg = (bid & 7) * (gridDim.x >> 3) + (bid >> 3);
    int wave = threadIdx.x >> 6, lane = threadIdx.x & 63;
    int pix = wg * 4 + wave;
    int n = pix / (HH*WWD); int rem = pix % (HH*WWD);
    int h = rem / WWD, w = rem % WWD;
    int c0 = lane * 4;
    float a0 = cb[c0+0], a1 = cb[c0+1], a2 = cb[c0+2], a3 = cb[c0+3];
    #pragma unroll
    for (int t = 0; t < 9; ++t) {
        int hh = h + t/3 - 1, wx = w + t%3 - 1;
        if (hh >= 0 && hh < HH && wx >= 0 && wx < WWD) {
            ushort4 xv = *reinterpret_cast<const ushort4*>(
                &xl[(((size_t)n*HH + hh)*WWD + wx)*CC + c0]);
            a0 += bf2f(xv.x) * w9[(c0+0)*9 + t];
            a1 += bf2f(xv.y) * w9[(c0+1)*9 + t];
            a2 += bf2f(xv.z) * w9[(c0+2)*9 + t];
            a3 += bf2f(xv.w) * w9[(c0+3)*9 + t];
        }
    }
    float s = a0+a1+a2+a3;
    float sq = a0*a0+a1*a1+a2*a2+a3*a3;
    wave_reduce2(s, sq);
    float mu = s*(1.f/256.f), var = sq*(1.f/256.f) - mu*mu;
    float rs = rsqrtf(var + 1e-6f);
    ushort4 o;
    o.x = f2bf(gelu_exact((a0-mu)*rs*lg[c0+0] + lb[c0+0]));
    o.y = f2bf(gelu_exact((a1-mu)*rs*lg[c0+1] + lb[c0+1]));
    o.z = f2bf(gelu_exact((a2-mu)*rs*lg[c0+2] + lb[c0+2]));
    o.w = f2bf(gelu_exact((a3-mu)*rs*lg[c0+3] + lb[c0+3]));
    *reinterpret_cast<ushort4*>(&out[(size_t)pix * CC + c0]) = o;
}

// ------- bf16 MFMA GEMM: depth-3 counted-vmcnt pipeline, BK=32, 4 LDS buffers -------
// C(MxN) = A(MxK,bf16) @ Bt(NpadxK,bf16)^T + bias.
// 128x128 tile, 4 waves (2x2 of 64x64), mfma_f32_16x16x32_bf16.
// Per step/wave: 4 gl_lds16 (A:2, B:2). Steady-state wait = vmcnt(8): tiles t+1,t+2
// stay in flight across the barrier (T4). Buf (t+3)&3 == (t-1)&3 is safe to overwrite
// after the iter-t barrier (its readers finished iter t-1 before arriving).
// EPI 1: bf16 gelu. EPI 2: fp32 extra1+extra2[c]*v. EPI 3: bf16 plain.
// EPI 4: fused off+mask -> Cf (cols<288) / Cf2 (288<=c<432).
template<int EPI>
__global__ __launch_bounds__(256) void gemm_bf16(
    const unsigned short* __restrict__ A, const unsigned short* __restrict__ Bt,
    const float* __restrict__ bias, float* __restrict__ Cf, float* __restrict__ Cf2,
    unsigned short* __restrict__ Cb, int M, int N, int K,
    const float* __restrict__ extra1, const float* __restrict__ extra2)
{
    __shared__ unsigned short Al[16384];   // 4 bufs x [kb:4][row:128][j:8]  (32 KB)
    __shared__ unsigned short Bl[16384];
    const int tid = threadIdx.x;
    const int wave = tid >> 6, lane = tid & 63;
    const int wr = wave >> 1, wc = wave & 1;
    const int lm = lane & 15, kq = lane >> 4;

    // XCD-chunked bijective remap of linear block id (nwg % 8 == 0)
    int bid = blockIdx.x + blockIdx.y * gridDim.x;
    int nwg = gridDim.x * gridDim.y;
    int wg = (bid & 7) * (nwg >> 3) + (bid >> 3);
    const int m0 = (wg / gridDim.x) * 128;
    const int n0 = (wg % gridDim.x) * 128;

    f32x4 acc[4][4];
    #pragma unroll
    for (int i = 0; i < 4; ++i)
        #pragma unroll
        for (int j = 0; j < 4; ++j)
            acc[i][j] = (f32x4){0.f, 0.f, 0.f, 0.f};

    const int arow = wr*64 + lm;
    const int brow = wc*64 + lm;

    auto STAGE = [&](int buf, int t) {
        int k0 = t << 5;
        #pragma unroll
        for (int i = 0; i < 2; ++i) {
            int idx = i*256 + tid;
            int kb = idx >> 7, row = idx & 127;
            int off = buf*8192 + i*4096 + wave*1024;   // bytes, wave-uniform
            gl_lds16(A  + (size_t)(m0+row)*K + k0 + kb*8, (char*)Al + off);
            gl_lds16(Bt + (size_t)(n0+row)*K + k0 + kb*8, (char*)Bl + off);
        }
    };

    const int nsteps = K >> 5;
    STAGE(0, 0); STAGE(1, 1); STAGE(2, 2);

    for (int t = 0; t < nsteps; ++t) {
        int buf = t & 3;
        int rem = nsteps - 1 - t;          // future tiles we want in flight
        if (rem >= 2)      asm volatile("s_waitcnt vmcnt(8)" ::: "memory");
        else if (rem == 1) asm volatile("s_waitcnt vmcnt(4)" ::: "memory");
        else               asm volatile("s_waitcnt vmcnt(0)" ::: "memory");
        __builtin_amdgcn_s_barrier();
        __builtin_amdgcn_sched_barrier(0);
        if (t + 3 < nsteps) STAGE((t+3) & 3, t+3);
        const unsigned short* Ab = &Al[buf*4096];
        const unsigned short* Bb = &Bl[buf*4096];
        bf16x8 af[4], bv[4];
        #pragma unroll
        for (int mi = 0; mi < 4; ++mi)
            af[mi] = *reinterpret_cast<const bf16x8*>(&Ab[(kq*128 + arow + mi*16)*8]);
        #pragma unroll
        for (int ni = 0; ni < 4; ++ni)
            bv[ni] = *reinterpret_cast<const bf16x8*>(&Bb[(kq*128 + brow + ni*16)*8]);
        #pragma unroll
        for (int mi = 0; mi < 4; ++mi)
            #pragma unroll
            for (int ni = 0; ni < 4; ++ni)
                acc[mi][ni] = __builtin_amdgcn_mfma_f32_16x16x32_bf16(
                    af[mi], bv[ni], acc[mi][ni], 0, 0, 0);
    }

    #pragma unroll
    for (int mi = 0; mi < 4; ++mi) {
        #pragma unroll
        for (int ni = 0; ni < 4; ++ni) {
            int c = n0 + wc*64 + ni*16 + lm;
            if (c < N) {
                float bb = bias[c];
                #pragma unroll
                for (int j = 0; j < 4; ++j) {
                    int r = m0 + wr*64 + mi*16 + kq*4 + j;
                    float v = acc[mi][ni][j] + bb;
                    if (EPI == 1) {
                        Cb[(size_t)r*N + c] = f2bf(gelu_exact(v));
                    } else if (EPI == 2) {
                        size_t gi = (size_t)r*N + c;
                        Cf[gi] = extra1[gi] + extra2[c]*v;
                    } else if (EPI == 3) {
                        Cb[(size_t)r*N + c] = f2bf(v);
                    } else {
                        if (c < 288)      Cf [(size_t)r*288 + c]       = v;
                        else if (c < 432) Cf2[(size_t)r*144 + (c-288)] = v;
                    }
                }
            }
        }
    }
}

__device__ __forceinline__ void tap4b(const unsigned short* __restrict__ img, int yi, int xi,
                                      float wgt, float4& s) {
    // padded coords; nonzero region is [1,56]
    if (yi >= 1 && yi <= 56 && xi >= 1 && xi <= 56) {
        ushort4 v = *reinterpret_cast<const ushort4*>(
            &img[(((size_t)(yi-1))*WWD + (xi-1)) * CC]);
        s.x += wgt*bf2f(v.x); s.y += wgt*bf2f(v.y);
        s.z += wgt*bf2f(v.z); s.w += wgt*bf2f(v.w);
    }
}

// Deformable sampling + fused 9-way softmax + mask aggregation.
// 1 wave/pixel; lane = (g, c4). msk holds RAW logits (softmax computed in-lane).
__global__ __launch_bounds__(256) void dcn_sample_kernel(
    const unsigned short* __restrict__ xproj, const float* __restrict__ offs,
    const float* __restrict__ msk, unsigned short* __restrict__ dcn)
{
    int bid = blockIdx.x;
    int wg = (bid & 7) * (gridDim.x >> 3) + (bid >> 3);
    int wave = threadIdx.x >> 6, lane = threadIdx.x & 63;
    int pix = wg * 4 + wave;
    int n = pix / (HH*WWD); int rem = pix % (HH*WWD);
    int h = rem / WWD, w = rem % WWD;
    int g = lane >> 2, c4 = lane & 3;
    const float* op = offs + (size_t)pix*288 + g*18;
    const float* mp = msk + (size_t)pix*144 + g*9;
    const unsigned short* img = xproj + (size_t)n*(HH*WWD*CC) + g*16 + c4*4;

    float mv[9]; float mx = -1e30f;
    #pragma unroll
    for (int j = 0; j < 9; ++j) { mv[j] = mp[j]; mx = fmaxf(mx, mv[j]); }
    float ssum = 0.f;
    #pragma unroll
    for (int j = 0; j < 9; ++j) { mv[j] = expf(mv[j]-mx); ssum += mv[j]; }
    float minv = 1.f/ssum;

    float4 acc = {0.f, 0.f, 0.f, 0.f};
    #pragma unroll
    for (int p = 0; p < 9; ++p) {
        float ox = op[p*2+0], oy = op[p*2+1];
        float xs = (float)(w + p/3) + ox;   // padded-image coords
        float ys = (float)(h + p%3) + oy;
        float x0f = floorf(xs), y0f = floorf(ys);
        float lx = xs - x0f, ly = ys - y0f;
        int x0 = (int)x0f, y0 = (int)y0f;
        float4 s = {0.f, 0.f, 0.f, 0.f};
        tap4b(img, y0,   x0,   (1.f-lx)*(1.f-ly), s);
        tap4b(img, y0,   x0+1, lx*(1.f-ly),       s);
        tap4b(img, y0+1, x0,   (1.f-lx)*ly,       s);
        tap4b(img, y0+1, x0+1, lx*ly,             s);
        float m = mv[p]*minv;
        acc.x += m*s.x; acc.y += m*s.y; acc.z += m*s.z; acc.w += m*s.w;
    }
    ushort4 o;
    o.x = f2bf(acc.x); o.y = f2bf(acc.y); o.z = f2bf(acc.z); o.w = f2bf(acc.w);
    *reinterpret_cast<ushort4*>(&dcn[(size_t)pix*CC + g*16 + c4*4]) = o;
}

extern "C" void kernel_launch(void* const* d_in, const int* in_sizes, int n_in,
                              void* d_out, int out_size, void* d_ws, size_t ws_size,
                              hipStream_t stream)
{
    const float* x    = (const float*)d_in[0];
    const float* n1g  = (const float*)d_in[1];
    const float* n1b  = (const float*)d_in[2];
    const float* n2g  = (const float*)d_in[3];
    const float* n2b  = (const float*)d_in[4];
    const float* g1   = (const float*)d_in[5];
    const float* g2   = (const float*)d_in[6];
    const float* dww  = (const float*)d_in[7];
    const float* dwb  = (const float*)d_in[8];
    const float* dlng = (const float*)d_in[9];
    const float* dlnb = (const float*)d_in[10];
    const float* offw = (const float*)d_in[11];
    const float* offb = (const float*)d_in[12];
    const float* mskw = (const float*)d_in[13];
    const float* mskb = (const float*)d_in[14];
    const float* inw  = (const float*)d_in[15];
    const float* inb  = (const float*)d_in[16];
    const float* outw = (const float*)d_in[17];
    const float* outb = (const float*)d_in[18];
    const float* f1w  = (const float*)d_in[19];
    const float* f1b  = (const float*)d_in[20];
    const float* f2w  = (const float*)d_in[21];
    const float* f2b  = (const float*)d_in[22];
    float* out = (float*)d_out;

    char* base = (char*)d_ws;
    // arena (bytes)
    unsigned short* xl_bf    = (unsigned short*)(base + 0);          // 12,845,056 B
    unsigned short* xproj_bf = (unsigned short*)(base + 12845056);   // 12,845,056 B
    float*          xres     = (float*)(base + 25690112);            // 25,690,112 B
    unsigned short* x1_bf    = (unsigned short*)(base + 51380224);   // 12,845,056 B
    float*          offs     = (float*)(base + 64225280);            // 28,901,376 B
    float*          msk      = (float*)(base + 93126656);            // 14,450,688 B
    unsigned short* dcn_bf   = xl_bf;                                 // reuse region A
    unsigned short* y2_bf    = x1_bf;                                 // reuse region C
    unsigned short* h1       = (unsigned short*)(base + 64225280);   // 51,380,224 B (over offs+msk)
    unsigned short* btb      = (unsigned short*)(base + 115605504);
    unsigned short* bt_in  = btb + 0;          // 256x256
    unsigned short* bt_om  = btb + 65536;      // 512x256
    unsigned short* bt_out = btb + 196608;     // 256x256
    unsigned short* bt_fc1 = btb + 262144;     // 1024x256
    unsigned short* bt_fc2 = btb + 524288;     // 256x1024
    float*          bias_om = (float*)(btb + 786432);  // 512 floats

    // 0. weight transposes (fp32 -> bf16, N-major)
    wtrans_kernel<<<256,  256, 0, stream>>>(inw,  bt_in,  256, 256,  256);
    wtrans_om_kernel<<<512, 256, 0, stream>>>(offw, offb, mskw, mskb, bt_om, bias_om);
    wtrans_kernel<<<256,  256, 0, stream>>>(outw, bt_out, 256, 256,  256);
    wtrans_kernel<<<1024, 256, 0, stream>>>(f1w,  bt_fc1, 256, 1024, 1024);
    wtrans_kernel<<<1024, 256, 0, stream>>>(f2w,  bt_fc2, 1024, 256, 256);

    // 1. LN1 -> xl (bf16)
    ln_bf_kernel<<<PIX/4, 256, 0, stream>>>(x, n1g, n1b, xl_bf);
    // 2. in_proj -> xproj (bf16)
    gemm_bf16<3><<<dim3(2,196), 256, 0, stream>>>(xl_bf, bt_in, inb, nullptr, nullptr,
        xproj_bf, PIX, 256, 256, nullptr, nullptr);
    // 3. depthwise conv + LN + GELU -> x1 (bf16)
    dwconv_ln_gelu_kernel<<<PIX/4, 256, 0, stream>>>(xl_bf, dww, dwb, dlng, dlnb, x1_bf);
    // 4. fused offset+mask GEMM (fp32 out, routed; msk gets raw logits)
    gemm_bf16<4><<<dim3(4,196), 256, 0, stream>>>(x1_bf, bt_om, bias_om, offs, msk,
        nullptr, PIX, 512, 256, nullptr, nullptr);
    // 5. deformable sampling + fused softmax -> dcn (bf16, reuses xl region)
    dcn_sample_kernel<<<PIX/4, 256, 0, stream>>>(xproj_bf, offs, msk, dcn_bf);
    // 6. out_proj + residual: xres = x + gamma1*(dcn@out_w + out_b)  (fp32)
    gemm_bf16<2><<<dim3(2,196), 256, 0, stream>>>(dcn_bf, bt_out, outb, xres, nullptr,
        nullptr, PIX, 256, 256, x, g1);
    // 7. LN2 -> y2 (bf16, reuses x1 region)
    ln_bf_kernel<<<PIX/4, 256, 0, stream>>>(xres, n2g, n2b, y2_bf);
    // 8. fc1 + gelu -> h1 (bf16)
    gemm_bf16<1><<<dim3(8,196), 256, 0, stream>>>(y2_bf, bt_fc1, f1b, nullptr, nullptr,
        h1, PIX, 1024, 256, nullptr, nullptr);
    // 9. fc2 + residual -> out (fp32)
    gemm_bf16<2><<<dim3(2,196), 256, 0, stream>>>(h1, bt_fc2, f2b, out, nullptr,
        nullptr, PIX, 256, 1024, xres, g2);
}